// Round 8
// baseline (447.981 us; speedup 1.0000x reference)
//
#include <hip/hip_runtime.h>

typedef float        f32x4  __attribute__((ext_vector_type(4)));
typedef __bf16       bf16x8 __attribute__((ext_vector_type(8)));
typedef __bf16       bf16x4 __attribute__((ext_vector_type(4)));
typedef unsigned int u32x4  __attribute__((ext_vector_type(4)));

#define NN   8192
#define IND  256
#define OUTD 128
#define KCHUNK 128
#define ASTR 136    // LDS row stride (bf16 elems): 272-B rows -> <=2-way alias (free)
#define BSTR 136

__device__ __forceinline__ bf16x8 cvt2(f32x4 a, f32x4 b) {
  bf16x8 r;
  r[0]=(__bf16)a[0]; r[1]=(__bf16)a[1]; r[2]=(__bf16)a[2]; r[3]=(__bf16)a[3];
  r[4]=(__bf16)b[0]; r[5]=(__bf16)b[1]; r[6]=(__bf16)b[2]; r[7]=(__bf16)b[3];
  return r;
}

// K1 (fused): Wh = X@W^T via MFMA (4-way K-split across waves, LDS merge),
// e = relu(Wh).a_w (16-lane butterfly allreduce), then write B^T directly:
// Bt[n][j] = exp(e_j)*Wh[j][n] (n<128), Bt[128][j] = exp(e_j), rows 129..143 = 0.
__global__ __launch_bounds__(256) void k1_bt(const float* __restrict__ X,
                                             const float* __restrict__ W,
                                             const float* __restrict__ aw,
                                             __bf16* __restrict__ Bt) {
  __shared__ float red[4][16][128];   // 32 KB
  const int tid  = threadIdx.x;
  const int lane = tid & 63;
  const int wave = tid >> 6;
  const int nlo  = lane & 15;
  const int quad = lane >> 4;
  const int rowBase = blockIdx.x * 16;

  const float* xp = X + (size_t)(rowBase + nlo) * IND + wave * 64 + quad * 8;
  f32x4 acc[8];
#pragma unroll
  for (int nt = 0; nt < 8; ++nt) acc[nt] = f32x4{0.f, 0.f, 0.f, 0.f};

#pragma unroll
  for (int kb = 0; kb < 64; kb += 32) {
    f32x4 a0 = *(const f32x4*)(xp + kb);
    f32x4 a1 = *(const f32x4*)(xp + kb + 4);
    bf16x8 af = cvt2(a0, a1);
#pragma unroll
    for (int nt = 0; nt < 8; ++nt) {
      const float* wp = W + (size_t)(nt * 16 + nlo) * IND + wave * 64 + kb + quad * 8;
      f32x4 b0 = *(const f32x4*)wp;
      f32x4 b1 = *(const f32x4*)(wp + 4);
      acc[nt] = __builtin_amdgcn_mfma_f32_16x16x32_bf16(af, cvt2(b0, b1), acc[nt], 0, 0, 0);
    }
  }
#pragma unroll
  for (int nt = 0; nt < 8; ++nt)
#pragma unroll
    for (int rg = 0; rg < 4; ++rg)
      red[wave][quad * 4 + rg][nt * 16 + nlo] = acc[nt][rg];
  __syncthreads();

  const int r  = tid >> 4;
  const int c0 = (tid & 15) * 8;
  f32x4 vlo = *(const f32x4*)&red[0][r][c0];
  f32x4 vhi = *(const f32x4*)&red[0][r][c0 + 4];
#pragma unroll
  for (int w = 1; w < 4; ++w) {
    vlo += *(const f32x4*)&red[w][r][c0];
    vhi += *(const f32x4*)&red[w][r][c0 + 4];
  }
  float pa = 0.f;
#pragma unroll
  for (int i = 0; i < 4; ++i) {
    pa += fmaxf(vlo[i], 0.f) * aw[c0 + i];
    pa += fmaxf(vhi[i], 0.f) * aw[c0 + 4 + i];
  }
#pragma unroll
  for (int off = 8; off; off >>= 1) pa += __shfl_xor(pa, off, 64);  // 16-lane allreduce
  const float wexp = expf(pa);
  const int j = rowBase + r;

#pragma unroll
  for (int i = 0; i < 4; ++i)
    Bt[(size_t)(c0 + i) * NN + j] = (__bf16)(vlo[i] * wexp);
#pragma unroll
  for (int i = 0; i < 4; ++i)
    Bt[(size_t)(c0 + 4 + i) * NN + j] = (__bf16)(vhi[i] * wexp);
  if ((tid & 15) == 0)
    Bt[(size_t)OUTD * NN + j] = (__bf16)wexp;           // denominator row
  if (tid < 120) {                                       // zero rows 129..143
    const int row = 129 + (tid >> 3);
    const int cc  = rowBase + (tid & 7) * 2;
    Bt[(size_t)row * NN + cc]     = (__bf16)0.f;
    Bt[(size_t)row * NN + cc + 1] = (__bf16)0.f;
  }
}

// K3 (fused, KSPLIT=1): out = relu( (A@B_num) / (A@b_den) ) computed in ONE pass
// over full K. Block = 32 rows, 4 waves = 2 rowgrps x 2 ntgrps (ntgrp0: ntiles
// 0..4, ntgrp1: 5..8). No accumulator cross-wave reduction (only the 16-float
// denominator crosses waves). part buffer + k3_reduce eliminated entirely.
// Bt restage per block = 2.25 MB, L2-resident (< 4 MB/XCD).
__global__ __launch_bounds__(256) void k3_fused(const float* __restrict__ Adj,
                                                const __bf16* __restrict__ Bt,
                                                float* __restrict__ out) {
  __shared__ unsigned short aT[32 * ASTR];   // 8.5 KB
  __shared__ unsigned short bT[144 * BSTR];  // 38.25 KB
  __shared__ float dend[32];
  const int tid  = threadIdx.x;
  const int lane = tid & 63;
  const int wv   = tid >> 6;
  const int nlo  = lane & 15;
  const int quad = lane >> 4;
  const int rowgrp = wv & 1;
  const int ntgrp  = wv >> 1;
  const int nt0 = ntgrp ? 5 : 0;
  const int ntn = ntgrp ? 4 : 5;   // ntgrp1's last acc (nt=8) = denominator tile
  const int rowBase = blockIdx.x * 32;

  // coalesced staging maps
  const int arow = tid >> 3;         // 0..31
  const int acol = (tid & 7) * 16;   // floats, 64 B contiguous per thread
  const int brow = tid >> 4;         // 0..15 (+ rr*16)
  const int bcol = (tid & 15) * 8;   // bf16, 16 B per thread

  const float*  aload = Adj + (size_t)(rowBase + arow) * NN + acol;
  const __bf16* bload = Bt + (size_t)brow * NN + bcol;

  f32x4 acc[5];
#pragma unroll
  for (int t = 0; t < 5; ++t) acc[t] = f32x4{0.f, 0.f, 0.f, 0.f};

  for (int c = 0; c < NN / KCHUNK; ++c) {
    const int kc = c * KCHUNK;
    // issue all global loads first; per-use waits drain progressively
    u32x4 breg[9];
#pragma unroll
    for (int rr = 0; rr < 9; ++rr)
      breg[rr] = *(const u32x4*)(bload + (size_t)(rr * 16) * NN + kc);
    f32x4 areg[4];
#pragma unroll
    for (int j = 0; j < 4; ++j)
      areg[j] = __builtin_nontemporal_load((const f32x4*)(aload + kc + j * 4));
#pragma unroll
    for (int rr = 0; rr < 9; ++rr)
      *(u32x4*)(bT + (rr * 16 + brow) * BSTR + bcol) = breg[rr];
    *(bf16x8*)(aT + arow * ASTR + acol)     = cvt2(areg[0], areg[1]);
    *(bf16x8*)(aT + arow * ASTR + acol + 8) = cvt2(areg[2], areg[3]);
    __syncthreads();

#pragma unroll
    for (int s = 0; s < 4; ++s) {
      bf16x8 af = *(const bf16x8*)(aT + (rowgrp * 16 + nlo) * ASTR + s * 32 + quad * 8);
#pragma unroll
      for (int t = 0; t < 5; ++t) {
        if (t < ntn) {
          bf16x8 bf = *(const bf16x8*)(bT + ((nt0 + t) * 16 + nlo) * BSTR + s * 32 + quad * 8);
          acc[t] = __builtin_amdgcn_mfma_f32_16x16x32_bf16(af, bf, acc[t], 0, 0, 0);
        }
      }
    }
    __syncthreads();
  }

  // denominator (ntgrp1, nt=8, col 128 lives at nlo==0) -> LDS -> all waves
  if (ntgrp == 1 && nlo == 0) {
#pragma unroll
    for (int rg = 0; rg < 4; ++rg)
      dend[rowgrp * 16 + quad * 4 + rg] = acc[3][rg];
  }
  __syncthreads();

  const int nstore = ntgrp ? 3 : 5;  // ntgrp1 stores nt 5..7 (col 128 excluded)
#pragma unroll
  for (int rg = 0; rg < 4; ++rg) {
    const float den = dend[rowgrp * 16 + quad * 4 + rg];
    const int row = rowBase + rowgrp * 16 + quad * 4 + rg;
#pragma unroll
    for (int t = 0; t < 5; ++t) {
      if (t < nstore)
        out[(size_t)row * OUTD + (nt0 + t) * 16 + nlo] = fmaxf(acc[t][rg] / den, 0.f);
    }
  }
}

extern "C" void kernel_launch(void* const* d_in, const int* in_sizes, int n_in,
                              void* d_out, int out_size, void* d_ws, size_t ws_size,
                              hipStream_t stream) {
  const float* X  = (const float*)d_in[0];
  const float* A  = (const float*)d_in[1];
  const float* W  = (const float*)d_in[2];
  const float* aw = (const float*)d_in[3];
  float* out = (float*)d_out;

  __bf16* Bt = (__bf16*)d_ws;                  // 144*8192*2 = 2.25 MiB

  k1_bt<<<512, 256, 0, stream>>>(X, W, aw, Bt);
  k3_fused<<<256, 256, 0, stream>>>(A, Bt, out);
}

// Round 9
// 438.131 us; speedup vs baseline: 1.0225x; 1.0225x over previous
//
#include <hip/hip_runtime.h>

typedef float        f32x4  __attribute__((ext_vector_type(4)));
typedef __bf16       bf16x8 __attribute__((ext_vector_type(8)));
typedef unsigned int u32x4  __attribute__((ext_vector_type(4)));

#define NN   8192
#define IND  256
#define OUTD 128
#define KCHUNK 128
#define ASTR 136    // LDS row stride (bf16 elems): 272-B rows -> <=2-way alias (free)
#define BSTR 136

__device__ __forceinline__ bf16x8 cvt2(f32x4 a, f32x4 b) {
  bf16x8 r;
  r[0]=(__bf16)a[0]; r[1]=(__bf16)a[1]; r[2]=(__bf16)a[2]; r[3]=(__bf16)a[3];
  r[4]=(__bf16)b[0]; r[5]=(__bf16)b[1]; r[6]=(__bf16)b[2]; r[7]=(__bf16)b[3];
  return r;
}

// K1 (fused): Wh = X@W^T via MFMA (4-way K-split across waves, LDS merge),
// e = relu(Wh).a_w (16-lane butterfly allreduce), then write B^T directly:
// Bt[n][j] = exp(e_j)*Wh[j][n] (n<128), Bt[128][j] = exp(e_j), rows 129..143 = 0.
__global__ __launch_bounds__(256) void k1_bt(const float* __restrict__ X,
                                             const float* __restrict__ W,
                                             const float* __restrict__ aw,
                                             __bf16* __restrict__ Bt) {
  __shared__ float red[4][16][128];   // 32 KB
  const int tid  = threadIdx.x;
  const int lane = tid & 63;
  const int wave = tid >> 6;
  const int nlo  = lane & 15;
  const int quad = lane >> 4;
  const int rowBase = blockIdx.x * 16;

  const float* xp = X + (size_t)(rowBase + nlo) * IND + wave * 64 + quad * 8;
  f32x4 acc[8];
#pragma unroll
  for (int nt = 0; nt < 8; ++nt) acc[nt] = f32x4{0.f, 0.f, 0.f, 0.f};

#pragma unroll
  for (int kb = 0; kb < 64; kb += 32) {
    f32x4 a0 = *(const f32x4*)(xp + kb);
    f32x4 a1 = *(const f32x4*)(xp + kb + 4);
    bf16x8 af = cvt2(a0, a1);
#pragma unroll
    for (int nt = 0; nt < 8; ++nt) {
      const float* wp = W + (size_t)(nt * 16 + nlo) * IND + wave * 64 + kb + quad * 8;
      f32x4 b0 = *(const f32x4*)wp;
      f32x4 b1 = *(const f32x4*)(wp + 4);
      acc[nt] = __builtin_amdgcn_mfma_f32_16x16x32_bf16(af, cvt2(b0, b1), acc[nt], 0, 0, 0);
    }
  }
#pragma unroll
  for (int nt = 0; nt < 8; ++nt)
#pragma unroll
    for (int rg = 0; rg < 4; ++rg)
      red[wave][quad * 4 + rg][nt * 16 + nlo] = acc[nt][rg];
  __syncthreads();

  const int r  = tid >> 4;
  const int c0 = (tid & 15) * 8;
  f32x4 vlo = *(const f32x4*)&red[0][r][c0];
  f32x4 vhi = *(const f32x4*)&red[0][r][c0 + 4];
#pragma unroll
  for (int w = 1; w < 4; ++w) {
    vlo += *(const f32x4*)&red[w][r][c0];
    vhi += *(const f32x4*)&red[w][r][c0 + 4];
  }
  float pa = 0.f;
#pragma unroll
  for (int i = 0; i < 4; ++i) {
    pa += fmaxf(vlo[i], 0.f) * aw[c0 + i];
    pa += fmaxf(vhi[i], 0.f) * aw[c0 + 4 + i];
  }
#pragma unroll
  for (int off = 8; off; off >>= 1) pa += __shfl_xor(pa, off, 64);  // 16-lane allreduce
  const float wexp = expf(pa);
  const int j = rowBase + r;

#pragma unroll
  for (int i = 0; i < 4; ++i)
    Bt[(size_t)(c0 + i) * NN + j] = (__bf16)(vlo[i] * wexp);
#pragma unroll
  for (int i = 0; i < 4; ++i)
    Bt[(size_t)(c0 + 4 + i) * NN + j] = (__bf16)(vhi[i] * wexp);
  if ((tid & 15) == 0)
    Bt[(size_t)OUTD * NN + j] = (__bf16)wexp;           // denominator row
  if (tid < 120) {                                       // zero rows 129..143
    const int row = 129 + (tid >> 3);
    const int cc  = rowBase + (tid & 7) * 2;
    Bt[(size_t)row * NN + cc]     = (__bf16)0.f;
    Bt[(size_t)row * NN + cc + 1] = (__bf16)0.f;
  }
}

// K3 (fused, R8-retry at R7 residency): out = relu((A@B_num)/(A@b_den)), one
// pass over full K. 512 blocks x 256 thr, block = 16 rows. Wave w owns n-tiles
// {w, w+4}; wave 0 additionally tile 8 (denominator). Disjoint output ->
// no cross-wave acc reduction; only 16 den floats cross waves.
// LDS 42.6 KB -> 3 blocks/CU = 12 waves/CU (R8's mistake was 1 blk/CU @ 4 waves).
__global__ __launch_bounds__(256, 3) void k3_fused(const float* __restrict__ Adj,
                                                   const __bf16* __restrict__ Bt,
                                                   float* __restrict__ out) {
  __shared__ unsigned short aT[16 * ASTR];   // 4.25 KB
  __shared__ unsigned short bT[144 * BSTR];  // 38.25 KB
  __shared__ float dend[16];
  const int tid  = threadIdx.x;
  const int lane = tid & 63;
  const int wv   = tid >> 6;     // 0..3
  const int nlo  = lane & 15;
  const int quad = lane >> 4;
  const int rowBase = blockIdx.x * 16;

  // coalesced staging map: 16 threads cover one row's 128-col chunk
  const int srow = tid >> 4;         // 0..15
  const int scol = (tid & 15) * 8;   // elems (floats for A, bf16 for B)

  const float*  aload = Adj + (size_t)(rowBase + srow) * NN + scol;
  const __bf16* bload = Bt + (size_t)srow * NN + scol;

  f32x4 acc0 = {0.f,0.f,0.f,0.f}, acc1 = {0.f,0.f,0.f,0.f}, acc2 = {0.f,0.f,0.f,0.f};

  for (int c = 0; c < NN / KCHUNK; ++c) {
    const int kc = c * KCHUNK;
    // issue all global loads first (B from L2, A streamed), single drain at sync
    u32x4 breg[9];
#pragma unroll
    for (int rr = 0; rr < 9; ++rr)
      breg[rr] = *(const u32x4*)(bload + (size_t)(rr * 16) * NN + kc);
    f32x4 a0 = __builtin_nontemporal_load((const f32x4*)(aload + kc));
    f32x4 a1 = __builtin_nontemporal_load((const f32x4*)(aload + kc + 4));
#pragma unroll
    for (int rr = 0; rr < 9; ++rr)
      *(u32x4*)(bT + (rr * 16 + srow) * BSTR + scol) = breg[rr];
    *(bf16x8*)(aT + srow * ASTR + scol) = cvt2(a0, a1);
    __syncthreads();

#pragma unroll
    for (int s = 0; s < 4; ++s) {
      bf16x8 af = *(const bf16x8*)(aT + nlo * ASTR + s * 32 + quad * 8);
      bf16x8 b0 = *(const bf16x8*)(bT + (wv * 16 + nlo) * BSTR + s * 32 + quad * 8);
      acc0 = __builtin_amdgcn_mfma_f32_16x16x32_bf16(af, b0, acc0, 0, 0, 0);
      bf16x8 b1 = *(const bf16x8*)(bT + ((wv + 4) * 16 + nlo) * BSTR + s * 32 + quad * 8);
      acc1 = __builtin_amdgcn_mfma_f32_16x16x32_bf16(af, b1, acc1, 0, 0, 0);
      if (wv == 0) {   // wave-uniform branch
        bf16x8 b2 = *(const bf16x8*)(bT + (128 + nlo) * BSTR + s * 32 + quad * 8);
        acc2 = __builtin_amdgcn_mfma_f32_16x16x32_bf16(af, b2, acc2, 0, 0, 0);
      }
    }
    __syncthreads();
  }

  // denominator: tile 8 col 0 (nlo==0 lanes of wave 0) -> LDS -> all waves
  if (wv == 0 && nlo == 0) {
#pragma unroll
    for (int rg = 0; rg < 4; ++rg) dend[quad * 4 + rg] = acc2[rg];
  }
  __syncthreads();

#pragma unroll
  for (int rg = 0; rg < 4; ++rg) {
    const int row = quad * 4 + rg;
    const float den = dend[row];
    out[(size_t)(rowBase + row) * OUTD + wv * 16 + nlo]       = fmaxf(acc0[rg] / den, 0.f);
    out[(size_t)(rowBase + row) * OUTD + (wv + 4) * 16 + nlo] = fmaxf(acc1[rg] / den, 0.f);
  }
}

extern "C" void kernel_launch(void* const* d_in, const int* in_sizes, int n_in,
                              void* d_out, int out_size, void* d_ws, size_t ws_size,
                              hipStream_t stream) {
  const float* X  = (const float*)d_in[0];
  const float* A  = (const float*)d_in[1];
  const float* W  = (const float*)d_in[2];
  const float* aw = (const float*)d_in[3];
  float* out = (float*)d_out;

  __bf16* Bt = (__bf16*)d_ws;                  // 144*8192*2 = 2.25 MiB

  k1_bt<<<512, 256, 0, stream>>>(X, W, aw, Bt);
  k3_fused<<<512, 256, 0, stream>>>(A, Bt, out);
}

// Round 10
// 400.045 us; speedup vs baseline: 1.1198x; 1.0952x over previous
//
#include <hip/hip_runtime.h>

typedef float        f32x4  __attribute__((ext_vector_type(4)));
typedef __bf16       bf16x8 __attribute__((ext_vector_type(8)));
typedef unsigned int u32x4  __attribute__((ext_vector_type(4)));

#define NN   8192
#define IND  256
#define OUTD 128
#define NB   144    // part cols: 0..127 = num, 128 = den, 129..143 never read
#define KSPLIT 8
#define KRANGE 1024 // 8192 / KSPLIT
#define KCHUNK 128
#define ASTR 136    // LDS row stride (bf16 elems): 272-B rows -> <=2-way alias (free)
#define BSTR 136

__device__ __forceinline__ bf16x8 cvt2(f32x4 a, f32x4 b) {
  bf16x8 r;
  r[0]=(__bf16)a[0]; r[1]=(__bf16)a[1]; r[2]=(__bf16)a[2]; r[3]=(__bf16)a[3];
  r[4]=(__bf16)b[0]; r[5]=(__bf16)b[1]; r[6]=(__bf16)b[2]; r[7]=(__bf16)b[3];
  return r;
}

// K1 (fused): Wh = X@W^T via MFMA (4-way K-split across waves, LDS merge),
// e = relu(Wh).a_w (16-lane butterfly allreduce), then write B^T directly:
// Bt[n][j] = exp(e_j)*Wh[j][n] (n<128), Bt[128][j] = exp(e_j), rows 129..143 = 0.
__global__ __launch_bounds__(256) void k1_bt(const float* __restrict__ X,
                                             const float* __restrict__ W,
                                             const float* __restrict__ aw,
                                             __bf16* __restrict__ Bt) {
  __shared__ float red[4][16][128];   // 32 KB
  const int tid  = threadIdx.x;
  const int lane = tid & 63;
  const int wave = tid >> 6;
  const int nlo  = lane & 15;
  const int quad = lane >> 4;
  const int rowBase = blockIdx.x * 16;

  const float* xp = X + (size_t)(rowBase + nlo) * IND + wave * 64 + quad * 8;
  f32x4 acc[8];
#pragma unroll
  for (int nt = 0; nt < 8; ++nt) acc[nt] = f32x4{0.f, 0.f, 0.f, 0.f};

#pragma unroll
  for (int kb = 0; kb < 64; kb += 32) {
    f32x4 a0 = *(const f32x4*)(xp + kb);
    f32x4 a1 = *(const f32x4*)(xp + kb + 4);
    bf16x8 af = cvt2(a0, a1);
#pragma unroll
    for (int nt = 0; nt < 8; ++nt) {
      const float* wp = W + (size_t)(nt * 16 + nlo) * IND + wave * 64 + kb + quad * 8;
      f32x4 b0 = *(const f32x4*)wp;
      f32x4 b1 = *(const f32x4*)(wp + 4);
      acc[nt] = __builtin_amdgcn_mfma_f32_16x16x32_bf16(af, cvt2(b0, b1), acc[nt], 0, 0, 0);
    }
  }
#pragma unroll
  for (int nt = 0; nt < 8; ++nt)
#pragma unroll
    for (int rg = 0; rg < 4; ++rg)
      red[wave][quad * 4 + rg][nt * 16 + nlo] = acc[nt][rg];
  __syncthreads();

  const int r  = tid >> 4;
  const int c0 = (tid & 15) * 8;
  f32x4 vlo = *(const f32x4*)&red[0][r][c0];
  f32x4 vhi = *(const f32x4*)&red[0][r][c0 + 4];
#pragma unroll
  for (int w = 1; w < 4; ++w) {
    vlo += *(const f32x4*)&red[w][r][c0];
    vhi += *(const f32x4*)&red[w][r][c0 + 4];
  }
  float pa = 0.f;
#pragma unroll
  for (int i = 0; i < 4; ++i) {
    pa += fmaxf(vlo[i], 0.f) * aw[c0 + i];
    pa += fmaxf(vhi[i], 0.f) * aw[c0 + 4 + i];
  }
#pragma unroll
  for (int off = 8; off; off >>= 1) pa += __shfl_xor(pa, off, 64);  // 16-lane allreduce
  const float wexp = expf(pa);
  const int j = rowBase + r;

#pragma unroll
  for (int i = 0; i < 4; ++i)
    Bt[(size_t)(c0 + i) * NN + j] = (__bf16)(vlo[i] * wexp);
#pragma unroll
  for (int i = 0; i < 4; ++i)
    Bt[(size_t)(c0 + 4 + i) * NN + j] = (__bf16)(vhi[i] * wexp);
  if ((tid & 15) == 0)
    Bt[(size_t)OUTD * NN + j] = (__bf16)wexp;           // denominator row
  if (tid < 120) {                                       // zero rows 129..143
    const int row = 129 + (tid >> 3);
    const int cc  = rowBase + (tid & 7) * 2;
    Bt[(size_t)row * NN + cc]     = (__bf16)0.f;
    Bt[(size_t)row * NN + cc + 1] = (__bf16)0.f;
  }
}

// K3a: part[slice][8192 x NB] = Adj(->bf16) @ B over slice's 1024-k range.
// Session-best structure (R7, 400.06 us total): A loaded COALESCED (16 lanes =
// 512 contiguous bytes of one row) and staged through LDS alongside B.
// 512 thr = 8 waves, 128 M-rows/block; LDS 72.25 KB -> 2 blocks/CU = 16 waves/CU.
__global__ __launch_bounds__(512, 4) void k3_partial(const float* __restrict__ Adj,
                                                     const __bf16* __restrict__ Bt,
                                                     float* __restrict__ part) {
  __shared__ unsigned short aT[128 * ASTR];  // 34 KB
  __shared__ unsigned short bT[NB * BSTR];   // 38.25 KB
  const int tid  = threadIdx.x;
  const int lane = tid & 63;
  const int wv   = tid >> 6;
  const int nlo  = lane & 15;
  const int quad = lane >> 4;
  const int rowW = blockIdx.x * 128 + wv * 16;
  const int k0   = blockIdx.y * KRANGE;

  // coalesced staging map: 16 threads cover one row's 128-col chunk
  const int lrow = tid >> 4;          // 0..31, + r*32 per round
  const int lcol = (tid & 15) * 8;    // elems (floats for A, bf16 for B)

  const float*  aload = Adj + (size_t)((size_t)blockIdx.x * 128 + lrow) * NN + k0 + lcol;
  const __bf16* bload = Bt + (size_t)lrow * NN + k0 + lcol;

  f32x4 acc[9];
#pragma unroll
  for (int nt = 0; nt < 9; ++nt) acc[nt] = f32x4{0.f, 0.f, 0.f, 0.f};

  for (int c = 0; c < KRANGE / KCHUNK; ++c) {
    const int kc = c * KCHUNK;
    // issue ALL global loads first (B then A), single drain at the barrier
    u32x4 breg[5];
#pragma unroll
    for (int r = 0; r < 4; ++r)
      breg[r] = *(const u32x4*)(bload + (size_t)(r * 32) * NN + kc);
    if (lrow < 16)  // rows 128..143 (denominator + zeros)
      breg[4] = *(const u32x4*)(bload + (size_t)128 * NN + kc);
    f32x4 areg[8];
#pragma unroll
    for (int r = 0; r < 4; ++r) {
      areg[2 * r]     = __builtin_nontemporal_load((const f32x4*)(aload + (size_t)(r * 32) * NN + kc));
      areg[2 * r + 1] = __builtin_nontemporal_load((const f32x4*)(aload + (size_t)(r * 32) * NN + kc + 4));
    }
    // LDS writes
#pragma unroll
    for (int r = 0; r < 4; ++r)
      *(u32x4*)(bT + (r * 32 + lrow) * BSTR + lcol) = breg[r];
    if (lrow < 16)
      *(u32x4*)(bT + (128 + lrow) * BSTR + lcol) = breg[4];
#pragma unroll
    for (int r = 0; r < 4; ++r)
      *(bf16x8*)(aT + (r * 32 + lrow) * ASTR + lcol) = cvt2(areg[2 * r], areg[2 * r + 1]);
    __syncthreads();

    // MFMA: fragments from LDS (A already bf16)
#pragma unroll
    for (int s = 0; s < 4; ++s) {
      bf16x8 af = *(const bf16x8*)(aT + (wv * 16 + nlo) * ASTR + s * 32 + quad * 8);
#pragma unroll
      for (int nt = 0; nt < 9; ++nt) {
        bf16x8 bf = *(const bf16x8*)(bT + (nt * 16 + nlo) * BSTR + s * 32 + quad * 8);
        acc[nt] = __builtin_amdgcn_mfma_f32_16x16x32_bf16(af, bf, acc[nt], 0, 0, 0);
      }
    }
    __syncthreads();
  }

  float* pbase = part + ((size_t)blockIdx.y * NN + rowW) * NB;
#pragma unroll
  for (int nt = 0; nt < 8; ++nt)
#pragma unroll
    for (int rg = 0; rg < 4; ++rg)
      pbase[(size_t)(quad * 4 + rg) * NB + nt * 16 + nlo] = acc[nt][rg];
  if (nlo == 0) {
#pragma unroll
    for (int rg = 0; rg < 4; ++rg)
      pbase[(size_t)(quad * 4 + rg) * NB + 128] = acc[8][rg];
  }
}

// K3b: out[row][col] = relu( sum_s part[s][row][col] / sum_s part[s][row][128] )
__global__ __launch_bounds__(256) void k3_reduce(const float* __restrict__ part,
                                                 float* __restrict__ out) {
  const int col = threadIdx.x & 127;
  const int row = blockIdx.x * 2 + (threadIdx.x >> 7);
  float num = 0.f, den = 0.f;
#pragma unroll
  for (int s = 0; s < KSPLIT; ++s) {
    const size_t base = ((size_t)s * NN + row) * NB;
    num += part[base + col];
    den += part[base + 128];
  }
  out[(size_t)row * OUTD + col] = fmaxf(num / den, 0.f);
}

extern "C" void kernel_launch(void* const* d_in, const int* in_sizes, int n_in,
                              void* d_out, int out_size, void* d_ws, size_t ws_size,
                              hipStream_t stream) {
  const float* X  = (const float*)d_in[0];
  const float* A  = (const float*)d_in[1];
  const float* W  = (const float*)d_in[2];
  const float* aw = (const float*)d_in[3];
  float* out = (float*)d_out;

  char* ws = (char*)d_ws;
  __bf16* Bt   = (__bf16*)ws;                   // 144*8192*2   = 2.25 MiB
  float*  part = (float*)(ws + 4194304);        // 8*8192*144*4 = 37.75 MiB

  k1_bt<<<512, 256, 0, stream>>>(X, W, aw, Bt);
  k3_partial<<<dim3(64, KSPLIT), 512, 0, stream>>>(A, Bt, part);
  k3_reduce<<<4096, 256, 0, stream>>>(part, out);
}